// Round 1
// 135.103 us; speedup vs baseline: 1.0028x; 1.0028x over previous
//
#include <hip/hip_runtime.h>
#include <math.h>

#define N_ATOMS   1500
#define NODE_DIM  128
#define HIDDEN    64
#define SPH_DIM   480
#define OFF0      128
#define MUL1E     64
#define HID1E     32
#define NUM_BASIS 20
#define NEDGE     (N_ATOMS * N_ATOMS)          // 2,250,000
#define JTILES    ((N_ATOMS + 255) / 256)      // 6
#define ITILE     2
#define IBLOCKS   (N_ATOMS / ITILE)            // 750 (1500 divisible by 2)

__device__ __forceinline__ float wave_reduce_sum64(float v) {
#pragma unroll
    for (int m = 1; m <= 32; m <<= 1) v += __shfl_xor(v, m, 64);
    return v;
}
__device__ __forceinline__ float half_reduce_sum32(float v) {
#pragma unroll
    for (int m = 1; m <= 16; m <<= 1) v += __shfl_xor(v, m, 64);
    return v;
}

// Phase 1: 375 blocks x 256 threads; wave w of block b handles node n = 4b+w.
// v2: stage the node's x-row (128 f32) and 1e-block row (192 f32) into LDS
// with ONE coalesced vector load per wave, then broadcast-read from LDS.
// This was previously 128+192 serialized same-address GLOBAL broadcast loads
// per wave at only ~1.5 waves/SIMD occupancy -> latency-critical.
__global__ __launch_bounds__(256) void node_precompute(
    const float* __restrict__ xs,   const float* __restrict__ xsph,
    const float* __restrict__ coord,
    const float* __restrict__ Wsi1, const float* __restrict__ Wsi2,
    const float* __restrict__ Wsj1, const float* __restrict__ Wsj2,
    const float* __restrict__ Wpi1, const float* __restrict__ Wpi2,
    const float* __restrict__ Wpj1, const float* __restrict__ Wpj2,
    float4* __restrict__ a4, float4* __restrict__ b4, float4* __restrict__ c4) {
    __shared__ float sx[4][NODE_DIM];        // per-wave x row
    __shared__ float sv[4][MUL1E * 3];       // per-wave 1e block row
    const int w    = threadIdx.x >> 6;
    const int lane = threadIdx.x & 63;
    const int n    = blockIdx.x * 4 + w;     // 375*4 = 1500 exact

    // cooperative stage (one float2 + one float4 per lane, coalesced)
    ((float2*)sx[w])[lane] = *(const float2*)(xs + n * NODE_DIM + lane * 2);
    if (lane < 48)
        ((float4*)sv[w])[lane] =
            *(const float4*)(xsph + n * SPH_DIM + OFF0 + lane * 4);
    __syncthreads();

    // ---- scalar MLPs: silu(x @ W1) @ W2, lane = hidden unit ----
    float zi = 0.f, zj = 0.f;
#pragma unroll 8
    for (int k = 0; k < NODE_DIM; ++k) {
        const float xv = sx[w][k];              // LDS broadcast
        zi += xv * Wsi1[k * HIDDEN + lane];     // coalesced, L2-resident
        zj += xv * Wsj1[k * HIDDEN + lane];
    }
    const float pi = zi / (1.f + __expf(-zi)) * Wsi2[lane];
    const float pj = zj / (1.f + __expf(-zj)) * Wsj2[lane];
    const float s_i = wave_reduce_sum64(pi);
    const float s_j = wave_reduce_sum64(pj);

    // ---- spherical 1e MLPs: lanes 0..31 -> Wpi, lanes 32..63 -> Wpj ----
    const int hh = lane & 31;
    const int which = lane >> 5;
    const float* W1 = which ? Wpj1 : Wpi1;      // [64,32]
    const float* W2 = which ? Wpj2 : Wpi2;      // [32,1]
    float a0 = 0.f, a1 = 0.f, a2 = 0.f;
#pragma unroll 4
    for (int m = 0; m < MUL1E; ++m) {
        const float wv = W1[m * HID1E + hh];
        a0 += sv[w][m * 3 + 0] * wv;            // LDS broadcast
        a1 += sv[w][m * 3 + 1] * wv;
        a2 += sv[w][m * 3 + 2] * wv;
    }
    a0 *= 0.125f; a1 *= 0.125f; a2 *= 0.125f;   // / sqrt(64)
    const float nrm = sqrtf(a0 * a0 + a1 * a1 + a2 * a2);
    const float gate = 1.f / (1.f + __expf(-nrm));
    const float w2 = W2[hh] * gate * 0.17677669529663687f;  // / sqrt(32)
    const float o0 = half_reduce_sum32(a0 * w2);
    const float o1 = half_reduce_sum32(a1 * w2);
    const float o2 = half_reduce_sum32(a2 * w2);
    // e3nn 1e (y,z,x) -> (x,y,z): result = (o2, o0, o1)
    if (lane == 0) {
        const float s = 1.f + s_i;
        a4[n] = make_float4(o2 * s, o0 * s, o1 * s, 0.f);
    } else if (lane == 32) {
        const float s = 1.f + s_j;
        b4[n] = make_float4(o2 * s, o0 * s, o1 * s, 0.f);
    } else if (lane == 16) {
        c4[n] = make_float4(coord[n * 3], coord[n * 3 + 1], coord[n * 3 + 2], 0.f);
    }
}

// Phase 2 v2: block = (j-tile of 256) x (2 consecutive i). j-gathers (aj,bj,cj)
// are loaded once and reused for both i rows; one __syncthreads per block;
// stores cover two contiguous 9 KB row segments.
//   out[i*N+j][r][c] = 0.5 * fc(d_ij) * (a_i[r]*b_j[c] + b_i[r]*a_j[c])
// NOTE: nontemporal stores are disqualified here — the harness's 0xAA poison
// fill leaves dirty d_out lines in L2, and their later eviction overwrites
// NT-stored data (verified divergence in a previous session). Plain stores only.
__global__ __launch_bounds__(256) void edge_kernel(
    const float4* __restrict__ a4, const float4* __restrict__ b4,
    const float4* __restrict__ c4, const float* __restrict__ Wrbf,
    float* __restrict__ out) {
    __shared__ float sm[ITILE * 256 * 9];               // 18 KB -> 8 blocks/CU
    const int i0 = blockIdx.y * ITILE;
    const int j0 = blockIdx.x * 256;
    const int j  = j0 + threadIdx.x;
    const int jj = (j < N_ATOMS) ? j : (N_ATOMS - 1);   // clamp; extras never stored

    const float4 aj = a4[jj], bj = b4[jj], cj = c4[jj]; // dwordx4 gathers

    float wk[NUM_BASIS];                                 // uniform -> SGPRs
#pragma unroll
    for (int k = 0; k < NUM_BASIS; ++k) wk[k] = Wrbf[k];

#pragma unroll
    for (int u = 0; u < ITILE; ++u) {
        const int i = i0 + u;
        const float4 ai = a4[i], bi = b4[i], ci = c4[i];    // uniform

        const float dx = ci.x - cj.x, dy = ci.y - cj.y, dz = ci.z - cj.z;
        const float d = sqrtf(dx * dx + dy * dy + dz * dz);

        // fc = 0.5 * sum_k Wrbf[k] * exp(-7.22*(d - 5k/19)^2)
        // direct form: exponent always <= 0, underflows cleanly (no overflow/NaN)
        float fc = 0.f;
#pragma unroll
        for (int k = 0; k < NUM_BASIS; ++k) {
            const float t = d - (float)(5.0 * k / 19.0);
            fc += wk[k] * __expf(-7.22f * (t * t));
        }
        fc *= 0.5f;

        // pre-scale rows by fc: 6 muls, then 9 mul + 9 fma
        const float fa0 = fc * ai.x, fa1 = fc * ai.y, fa2 = fc * ai.z;
        const float fb0 = fc * bi.x, fb1 = fc * bi.y, fb2 = fc * bi.z;

        // stage edge-major in LDS (stride 9 floats -> 2-way bank alias, free)
        float* s = sm + u * (256 * 9) + threadIdx.x * 9;
        s[0] = fa0 * bj.x + fb0 * aj.x;
        s[1] = fa0 * bj.y + fb0 * aj.y;
        s[2] = fa0 * bj.z + fb0 * aj.z;
        s[3] = fa1 * bj.x + fb1 * aj.x;
        s[4] = fa1 * bj.y + fb1 * aj.y;
        s[5] = fa1 * bj.z + fb1 * aj.z;
        s[6] = fa2 * bj.x + fb2 * aj.x;
        s[7] = fa2 * bj.y + fb2 * aj.y;
        s[8] = fa2 * bj.z + fb2 * aj.z;
    }
    __syncthreads();

    // coalesced float4 stores of this block's two contiguous row segments
    const int nj  = min(N_ATOMS - j0, 256);
    const int nf4 = nj * 9 / 4;                  // 576 full, 495 tail (exact)
    const float4* sm4 = (const float4*)sm;
#pragma unroll
    for (int u = 0; u < ITILE; ++u) {
        float4* out4 = (float4*)out + ((size_t)(i0 + u) * N_ATOMS + j0) * 9 / 4;
        const float4* s4 = sm4 + u * (256 * 9 / 4);
        for (int t = threadIdx.x; t < nf4; t += 256) out4[t] = s4[t];
    }
}

extern "C" void kernel_launch(void* const* d_in, const int* in_sizes, int n_in,
                              void* d_out, int out_size, void* d_ws, size_t ws_size,
                              hipStream_t stream) {
    const float* x_scalar = (const float*)d_in[0];
    const float* x_sph    = (const float*)d_in[1];
    const float* coord    = (const float*)d_in[2];
    // d_in[3] = fc_edge_index (int32) — known i-major full graph, unused
    const float* Wsi1 = (const float*)d_in[4];
    const float* Wsi2 = (const float*)d_in[5];
    const float* Wsj1 = (const float*)d_in[6];
    const float* Wsj2 = (const float*)d_in[7];
    const float* Wpi1 = (const float*)d_in[8];
    const float* Wpi2 = (const float*)d_in[9];
    const float* Wpj1 = (const float*)d_in[10];
    const float* Wpj2 = (const float*)d_in[11];
    const float* Wrbf = (const float*)d_in[12];
    float* out = (float*)d_out;

    float4* a4 = (float4*)d_ws;          // [N]
    float4* b4 = a4 + N_ATOMS;           // [N]
    float4* c4 = b4 + N_ATOMS;           // [N]

    node_precompute<<<375, 256, 0, stream>>>(
        x_scalar, x_sph, coord, Wsi1, Wsi2, Wsj1, Wsj2,
        Wpi1, Wpi2, Wpj1, Wpj2, a4, b4, c4);

    dim3 grid(JTILES, IBLOCKS);          // (6, 750)
    edge_kernel<<<grid, 256, 0, stream>>>(a4, b4, c4, Wrbf, out);
}